// Round 1
// baseline (317.004 us; speedup 1.0000x reference)
//
#include <hip/hip_runtime.h>

typedef __attribute__((ext_vector_type(4))) float f32x4;
typedef __attribute__((ext_vector_type(8))) short bf16x8;

#define LOG2E 1.4426950408889634f

__device__ __forceinline__ unsigned short f2bf(float f) {
  union { float f; unsigned u; } v; v.f = f;
  unsigned r = v.u + 0x7fffu + ((v.u >> 16) & 1u);
  return (unsigned short)(r >> 16);
}

// C[M,N] = X[M,K] @ W[N,K]^T + bias ; M=4096, N=1024, K=1024
// IN_BF16: 0 = X is fp32, 1 = X is bf16 (ushort)
// OUT_MODE: 0 = bf16 head-major [B,H,S,HD]; 1 = bf16 V^T [B,H,HD,S]; 2 = fp32 row-major
template<int IN_BF16, int OUT_MODE>
__global__ __launch_bounds__(256) void gemm_kernel(
    const void* __restrict__ Xv, const float* __restrict__ W,
    const float* __restrict__ bias, void* __restrict__ Outv)
{
  constexpr int N = 1024, K = 1024;
  __shared__ __align__(16) unsigned short lA[128 * 32];
  __shared__ __align__(16) unsigned short lB[128 * 32];
  const int n0 = blockIdx.x * 128;
  const int m0 = blockIdx.y * 128;
  const int tid = threadIdx.x;
  const int w = tid >> 6, lane = tid & 63, lr = lane & 15, lg = lane >> 4;
  const int wm = (w >> 1) * 64, wn = (w & 1) * 64;

  f32x4 acc[4][4] = {};

  for (int kt = 0; kt < K; kt += 32) {
    // stage W tile (fp32 -> bf16): 128 rows (output cols) x 32 k
    #pragma unroll
    for (int it = 0; it < 4; ++it) {
      int idx = it * 256 + tid;
      int row = idx >> 3, c4 = idx & 7;
      float4 xv = *reinterpret_cast<const float4*>(&W[(size_t)(n0 + row) * K + kt + c4 * 4]);
      unsigned short* dst = &lB[row * 32 + c4 * 4];
      dst[0] = f2bf(xv.x); dst[1] = f2bf(xv.y); dst[2] = f2bf(xv.z); dst[3] = f2bf(xv.w);
    }
    // stage X tile
    if (IN_BF16 == 0) {
      const float* X = (const float*)Xv;
      #pragma unroll
      for (int it = 0; it < 4; ++it) {
        int idx = it * 256 + tid;
        int row = idx >> 3, c4 = idx & 7;
        float4 xv = *reinterpret_cast<const float4*>(&X[(size_t)(m0 + row) * K + kt + c4 * 4]);
        unsigned short* dst = &lA[row * 32 + c4 * 4];
        dst[0] = f2bf(xv.x); dst[1] = f2bf(xv.y); dst[2] = f2bf(xv.z); dst[3] = f2bf(xv.w);
      }
    } else {
      const unsigned short* X = (const unsigned short*)Xv;
      #pragma unroll
      for (int it = 0; it < 2; ++it) {
        int idx = it * 256 + tid;
        int row = idx >> 2, c = idx & 3;
        *reinterpret_cast<uint4*>(&lA[row * 32 + c * 8]) =
            *reinterpret_cast<const uint4*>(&X[(size_t)(m0 + row) * K + kt + c * 8]);
      }
    }
    __syncthreads();

    bf16x8 af[4], bfr[4];
    #pragma unroll
    for (int i = 0; i < 4; ++i) {
      af[i]  = *reinterpret_cast<const bf16x8*>(&lA[(wm + i * 16 + lr) * 32 + lg * 8]);
      bfr[i] = *reinterpret_cast<const bf16x8*>(&lB[(wn + i * 16 + lr) * 32 + lg * 8]);
    }
    #pragma unroll
    for (int mi = 0; mi < 4; ++mi)
      #pragma unroll
      for (int ni = 0; ni < 4; ++ni)
        acc[mi][ni] = __builtin_amdgcn_mfma_f32_16x16x32_bf16(af[mi], bfr[ni], acc[mi][ni], 0, 0, 0);
    __syncthreads();
  }

  // epilogue: C row = m0+wm+mi*16 + lg*4+r ; C col = n0+wn+ni*16 + lr
  #pragma unroll
  for (int mi = 0; mi < 4; ++mi) {
    #pragma unroll
    for (int ni = 0; ni < 4; ++ni) {
      int col = n0 + wn + ni * 16 + lr;
      float bv = bias[col];
      #pragma unroll
      for (int r = 0; r < 4; ++r) {
        int row = m0 + wm + mi * 16 + lg * 4 + r;
        float val = acc[mi][ni][r] + bv;
        if (OUT_MODE == 2) {
          ((float*)Outv)[(size_t)row * N + col] = val;
        } else {
          int b = row >> 11, s = row & 2047;
          int h = col >> 6, hd = col & 63;
          unsigned short* O = (unsigned short*)Outv;
          if (OUT_MODE == 0)
            O[((size_t)(b * 16 + h) * 2048 + s) * 64 + hd] = f2bf(val);
          else
            O[((size_t)(b * 16 + h) * 64 + hd) * 2048 + s] = f2bf(val);
        }
      }
    }
  }
}

// Causal flash attention. Grid: (S/64, B*H). 4 waves; wave w owns q rows [q0+16w, q0+16w+16).
// Qh/Kh: [B,H,S,HD] bf16 ; Vt: [B,H,HD,S] bf16 ; Oa: [B,S,H*HD] bf16.
__global__ __launch_bounds__(256) void attn_kernel(
    const unsigned short* __restrict__ Qh, const unsigned short* __restrict__ Kh,
    const unsigned short* __restrict__ Vt, unsigned short* __restrict__ Oa)
{
  __shared__ __align__(16) unsigned short lK[64 * 64];
  __shared__ __align__(16) unsigned short lV[64 * 64];   // [d][k]
  __shared__ __align__(16) unsigned short lP[4][16 * 64];
  const int qt = blockIdx.x, bh = blockIdx.y;
  const int b = bh >> 4, h = bh & 15;
  const int q0 = qt * 64;
  const unsigned short* Qb = Qh + (size_t)bh * 2048 * 64;
  const unsigned short* Kb = Kh + (size_t)bh * 2048 * 64;
  const unsigned short* Vb = Vt + (size_t)bh * 64 * 2048;
  const int tid = threadIdx.x, w = tid >> 6, lane = tid & 63, lr = lane & 15, lg = lane >> 4;

  // Q fragments for this wave's 16 rows (A-layout: row=lane&15, k=8*(lane>>4)+j)
  bf16x8 aq[2];
  {
    int qrow = q0 + w * 16 + lr;
    aq[0] = *reinterpret_cast<const bf16x8*>(&Qb[(size_t)qrow * 64 + lg * 8]);
    aq[1] = *reinterpret_cast<const bf16x8*>(&Qb[(size_t)qrow * 64 + 32 + lg * 8]);
  }
  f32x4 oacc[4] = {};
  float mrow[4] = {-3e38f, -3e38f, -3e38f, -3e38f};
  float lrow[4] = {0.f, 0.f, 0.f, 0.f};

  const int nkt = qt + 1;
  for (int kt = 0; kt < nkt; ++kt) {
    #pragma unroll
    for (int it = 0; it < 2; ++it) {
      int idx = it * 256 + tid;
      int row = idx >> 3, c = idx & 7;
      *reinterpret_cast<uint4*>(&lK[row * 64 + c * 8]) =
          *reinterpret_cast<const uint4*>(&Kb[(size_t)(kt * 64 + row) * 64 + c * 8]);
      *reinterpret_cast<uint4*>(&lV[row * 64 + c * 8]) =
          *reinterpret_cast<const uint4*>(&Vb[(size_t)row * 2048 + kt * 64 + c * 8]);
    }
    __syncthreads();

    // scores: 16 x 64 per wave
    f32x4 sc[4] = {};
    #pragma unroll
    for (int nf = 0; nf < 4; ++nf) {
      bf16x8 b0 = *reinterpret_cast<const bf16x8*>(&lK[(nf * 16 + lr) * 64 + lg * 8]);
      bf16x8 b1 = *reinterpret_cast<const bf16x8*>(&lK[(nf * 16 + lr) * 64 + 32 + lg * 8]);
      sc[nf] = __builtin_amdgcn_mfma_f32_16x16x32_bf16(aq[0], b0, sc[nf], 0, 0, 0);
      sc[nf] = __builtin_amdgcn_mfma_f32_16x16x32_bf16(aq[1], b1, sc[nf], 0, 0, 0);
    }
    const bool diag = (kt == qt);
    float pm[4] = {-3e38f, -3e38f, -3e38f, -3e38f};
    #pragma unroll
    for (int nf = 0; nf < 4; ++nf)
      #pragma unroll
      for (int r = 0; r < 4; ++r) {
        float s = sc[nf][r] * 0.125f;   // 1/sqrt(64)
        if (diag && (kt * 64 + nf * 16 + lr) > (q0 + w * 16 + lg * 4 + r)) s = -1e30f;
        sc[nf][r] = s;
        pm[r] = fmaxf(pm[r], s);
      }
    // row reduce across the 16-lane group (cols live on lanes 0..15 of each group)
    #pragma unroll
    for (int r = 0; r < 4; ++r) {
      #pragma unroll
      for (int x = 1; x < 16; x <<= 1) pm[r] = fmaxf(pm[r], __shfl_xor(pm[r], x));
    }
    float mnew[4], al[4], rs[4] = {0.f, 0.f, 0.f, 0.f};
    #pragma unroll
    for (int r = 0; r < 4; ++r) {
      mnew[r] = fmaxf(mrow[r], pm[r]);
      al[r] = exp2f((mrow[r] - mnew[r]) * LOG2E);
      mrow[r] = mnew[r];
    }
    #pragma unroll
    for (int nf = 0; nf < 4; ++nf)
      #pragma unroll
      for (int r = 0; r < 4; ++r) {
        float p = exp2f((sc[nf][r] - mnew[r]) * LOG2E);
        sc[nf][r] = p;
        rs[r] += p;
      }
    #pragma unroll
    for (int r = 0; r < 4; ++r) {
      #pragma unroll
      for (int x = 1; x < 16; x <<= 1) rs[r] += __shfl_xor(rs[r], x);
      lrow[r] = lrow[r] * al[r] + rs[r];
    }
    #pragma unroll
    for (int df = 0; df < 4; ++df)
      #pragma unroll
      for (int r = 0; r < 4; ++r) oacc[df][r] *= al[r];

    // P (16x64) -> per-wave LDS, then reload in A-fragment layout
    unsigned short* pw = &lP[w][0];
    #pragma unroll
    for (int nf = 0; nf < 4; ++nf)
      #pragma unroll
      for (int r = 0; r < 4; ++r)
        pw[(lg * 4 + r) * 64 + nf * 16 + lr] = f2bf(sc[nf][r]);
    bf16x8 pa0 = *reinterpret_cast<const bf16x8*>(&pw[lr * 64 + lg * 8]);
    bf16x8 pa1 = *reinterpret_cast<const bf16x8*>(&pw[lr * 64 + 32 + lg * 8]);

    #pragma unroll
    for (int df = 0; df < 4; ++df) {
      bf16x8 v0 = *reinterpret_cast<const bf16x8*>(&lV[(df * 16 + lr) * 64 + lg * 8]);
      bf16x8 v1 = *reinterpret_cast<const bf16x8*>(&lV[(df * 16 + lr) * 64 + 32 + lg * 8]);
      oacc[df] = __builtin_amdgcn_mfma_f32_16x16x32_bf16(pa0, v0, oacc[df], 0, 0, 0);
      oacc[df] = __builtin_amdgcn_mfma_f32_16x16x32_bf16(pa1, v1, oacc[df], 0, 0, 0);
    }
    __syncthreads();
  }

  // normalize + store to [B,S,H*HD] bf16
  #pragma unroll
  for (int df = 0; df < 4; ++df)
    #pragma unroll
    for (int r = 0; r < 4; ++r) {
      int s = q0 + w * 16 + lg * 4 + r;
      int d = df * 16 + lr;
      float val = oacc[df][r] / lrow[r];
      Oa[(size_t)(b * 2048 + s) * 1024 + h * 64 + d] = f2bf(val);
    }
}

extern "C" void kernel_launch(void* const* d_in, const int* in_sizes, int n_in,
                              void* d_out, int out_size, void* d_ws, size_t ws_size,
                              hipStream_t stream) {
  const float* q  = (const float*)d_in[0];
  const float* k  = (const float*)d_in[1];
  const float* v  = (const float*)d_in[2];
  const float* Wq = (const float*)d_in[4];
  const float* bq = (const float*)d_in[5];
  const float* Wk = (const float*)d_in[6];
  const float* bk = (const float*)d_in[7];
  const float* Wv = (const float*)d_in[8];
  const float* bv = (const float*)d_in[9];
  const float* Wf = (const float*)d_in[10];
  const float* bf = (const float*)d_in[11];

  unsigned short* Qh = (unsigned short*)d_ws;
  unsigned short* Kh = Qh + (size_t)4096 * 1024;
  unsigned short* Vt = Kh + (size_t)4096 * 1024;
  unsigned short* Oa = Vt + (size_t)4096 * 1024;

  dim3 gg(8, 32), gb(256);
  gemm_kernel<0, 0><<<gg, gb, 0, stream>>>(q, Wq, bq, Qh);
  gemm_kernel<0, 0><<<gg, gb, 0, stream>>>(k, Wk, bk, Kh);
  gemm_kernel<0, 1><<<gg, gb, 0, stream>>>(v, Wv, bv, Vt);
  attn_kernel<<<dim3(32, 32), gb, 0, stream>>>(Qh, Kh, Vt, Oa);
  gemm_kernel<1, 2><<<gg, gb, 0, stream>>>(Oa, Wf, bf, (float*)d_out);
}

// Round 2
// 211.147 us; speedup vs baseline: 1.5013x; 1.5013x over previous
//
#include <hip/hip_runtime.h>

typedef __attribute__((ext_vector_type(4))) float f32x4;
typedef __attribute__((ext_vector_type(8))) short bf16x8;
typedef unsigned short u16;
typedef unsigned int u32;

#define QSCALE 0.18033688011112042f  // (1/sqrt(64)) * log2(e), folded into Q proj

__device__ __forceinline__ u16 f2bf(float f) {
  union { float f; u32 u; } v; v.f = f;
  u32 r = v.u + 0x7fffu + ((v.u >> 16) & 1u);
  return (u16)(r >> 16);
}

// async global->LDS, 16B per lane; LDS dest = base + lane*16 (wave-uniform base)
__device__ __forceinline__ void gl_lds16(const u16* g, u16* l) {
  __builtin_amdgcn_global_load_lds((const __attribute__((address_space(1))) u32*)g,
                                   (__attribute__((address_space(3))) u32*)l, 16, 0, 0);
}

// ---------------- fp32 -> bf16 bulk convert (q,k,v,Wq,Wk,Wv,Wf) ----------------
__global__ __launch_bounds__(256) void conv_kernel(
    const float* __restrict__ q, const float* __restrict__ k, const float* __restrict__ v,
    const float* __restrict__ wq, const float* __restrict__ wk, const float* __restrict__ wv,
    const float* __restrict__ wf, u16* __restrict__ dst)
{
  size_t i = ((size_t)blockIdx.x * 256 + threadIdx.x) * 8;  // 16M elems total
  const float* src; size_t off;
  if (i < ((size_t)3 << 22)) {
    int a = (int)(i >> 22);
    src = (a == 0) ? q : ((a == 1) ? k : v);
    off = i & ((1u << 22) - 1);
  } else {
    size_t j = i - ((size_t)3 << 22);
    int a = (int)(j >> 20);
    src = (a == 0) ? wq : ((a == 1) ? wk : ((a == 2) ? wv : wf));
    off = j & ((1u << 20) - 1);
  }
  float4 x0 = *reinterpret_cast<const float4*>(src + off);
  float4 x1 = *reinterpret_cast<const float4*>(src + off + 4);
  u16 o[8] = {f2bf(x0.x), f2bf(x0.y), f2bf(x0.z), f2bf(x0.w),
              f2bf(x1.x), f2bf(x1.y), f2bf(x1.z), f2bf(x1.w)};
  *reinterpret_cast<uint4*>(dst + i) = *reinterpret_cast<const uint4*>(o);
}

// ---------------- bf16 GEMM: C[M,N]=X[M,K]@W[N,K]^T+b ; BK=64, swizzled LDS ----
// mode: 0 = bf16 head-major [B,H,S,HD] (*scale); 1 = bf16 V^T [B,H,HD,S]; 2 = fp32
struct GArg {
  const u16* X; const u16* W; const float* bias; void* out; int mode; float scale;
};

template<int BM>
__global__ __launch_bounds__(256) void gemm_bf(GArg a0, GArg a1, GArg a2) {
  constexpr int K = 1024, N = 1024;
  constexpr int WNw = (BM == 128) ? 2 : 4;   // waves across N
  constexpr int NI  = (128 / WNw) / 16;      // 4 (BM=128) or 2 (BM=64)
  constexpr int CA  = BM / 32;               // A-stage calls per wave
  __shared__ __align__(16) u16 lA[BM * 64];
  __shared__ __align__(16) u16 lB[128 * 64];
  GArg a = (blockIdx.z == 0) ? a0 : ((blockIdx.z == 1) ? a1 : a2);
  const int n0 = blockIdx.x * 128, m0 = blockIdx.y * BM;
  const int tid = threadIdx.x, w = tid >> 6, lane = tid & 63;
  const int lr = lane & 15, lg = lane >> 4;
  const int wm = (w / WNw) * 64, wn = (w % WNw) * (128 / WNw);
  const int lrow8 = lane >> 3, lc = lane & 7;
  const int schunk = (lc ^ lrow8) * 8;       // pre-swizzled source chunk (u16 offs)

  f32x4 acc[4][NI] = {};

  for (int kt = 0; kt < K; kt += 64) {
    #pragma unroll
    for (int c = 0; c < CA; ++c) {
      int row = w * (BM / 4) + c * 8 + lrow8;
      gl_lds16(a.X + (size_t)(m0 + row) * K + kt + schunk, &lA[(w * (BM / 4) + c * 8) * 64]);
    }
    #pragma unroll
    for (int c = 0; c < 4; ++c) {
      int row = w * 32 + c * 8 + lrow8;
      gl_lds16(a.W + (size_t)(n0 + row) * K + kt + schunk, &lB[(w * 32 + c * 8) * 64]);
    }
    __syncthreads();
    #pragma unroll
    for (int h = 0; h < 2; ++h) {
      bf16x8 af[4], bfv[NI];
      #pragma unroll
      for (int i = 0; i < 4; ++i) {
        int r = wm + i * 16 + lr;
        af[i] = *reinterpret_cast<const bf16x8*>(&lA[r * 64 + (((h * 4 + lg) ^ (r & 7)) * 8)]);
      }
      #pragma unroll
      for (int i = 0; i < NI; ++i) {
        int r = wn + i * 16 + lr;
        bfv[i] = *reinterpret_cast<const bf16x8*>(&lB[r * 64 + (((h * 4 + lg) ^ (r & 7)) * 8)]);
      }
      __builtin_amdgcn_s_setprio(1);
      #pragma unroll
      for (int mi = 0; mi < 4; ++mi)
        #pragma unroll
        for (int ni = 0; ni < NI; ++ni)
          acc[mi][ni] = __builtin_amdgcn_mfma_f32_16x16x32_bf16(af[mi], bfv[ni], acc[mi][ni], 0, 0, 0);
      __builtin_amdgcn_s_setprio(0);
    }
    __syncthreads();
  }

  #pragma unroll
  for (int mi = 0; mi < 4; ++mi) {
    #pragma unroll
    for (int ni = 0; ni < NI; ++ni) {
      int col = n0 + wn + ni * 16 + lr;
      float bv = a.bias[col];
      #pragma unroll
      for (int r = 0; r < 4; ++r) {
        int row = m0 + wm + mi * 16 + lg * 4 + r;
        float val = (acc[mi][ni][r] + bv) * a.scale;
        if (a.mode == 2) {
          ((float*)a.out)[(size_t)row * N + col] = val;
        } else {
          int b = row >> 11, s = row & 2047, hh = col >> 6, hd = col & 63;
          u16* O = (u16*)a.out;
          if (a.mode == 0) O[((size_t)(b * 16 + hh) * 2048 + s) * 64 + hd] = f2bf(val);
          else             O[((size_t)(b * 16 + hh) * 64 + hd) * 2048 + s] = f2bf(val);
        }
      }
    }
  }
}

// ---------------- legacy fp32-staging GEMM (ws fallback) -----------------------
template<int IN_BF16, int OUT_MODE>
__global__ __launch_bounds__(256) void gemm_legacy(
    const void* __restrict__ Xv, const float* __restrict__ W,
    const float* __restrict__ bias, void* __restrict__ Outv, float scale)
{
  constexpr int N = 1024, K = 1024;
  __shared__ __align__(16) u16 lA[128 * 32];
  __shared__ __align__(16) u16 lB[128 * 32];
  const int n0 = blockIdx.x * 128, m0 = blockIdx.y * 128;
  const int tid = threadIdx.x;
  const int w = tid >> 6, lane = tid & 63, lr = lane & 15, lg = lane >> 4;
  const int wm = (w >> 1) * 64, wn = (w & 1) * 64;
  f32x4 acc[4][4] = {};
  for (int kt = 0; kt < K; kt += 32) {
    #pragma unroll
    for (int it = 0; it < 4; ++it) {
      int idx = it * 256 + tid, row = idx >> 3, c4 = idx & 7;
      float4 xv = *reinterpret_cast<const float4*>(&W[(size_t)(n0 + row) * K + kt + c4 * 4]);
      u16* dst = &lB[row * 32 + c4 * 4];
      dst[0] = f2bf(xv.x); dst[1] = f2bf(xv.y); dst[2] = f2bf(xv.z); dst[3] = f2bf(xv.w);
    }
    if (IN_BF16 == 0) {
      const float* X = (const float*)Xv;
      #pragma unroll
      for (int it = 0; it < 4; ++it) {
        int idx = it * 256 + tid, row = idx >> 3, c4 = idx & 7;
        float4 xv = *reinterpret_cast<const float4*>(&X[(size_t)(m0 + row) * K + kt + c4 * 4]);
        u16* dst = &lA[row * 32 + c4 * 4];
        dst[0] = f2bf(xv.x); dst[1] = f2bf(xv.y); dst[2] = f2bf(xv.z); dst[3] = f2bf(xv.w);
      }
    } else {
      const u16* X = (const u16*)Xv;
      #pragma unroll
      for (int it = 0; it < 2; ++it) {
        int idx = it * 256 + tid, row = idx >> 2, c = idx & 3;
        *reinterpret_cast<uint4*>(&lA[row * 32 + c * 8]) =
            *reinterpret_cast<const uint4*>(&X[(size_t)(m0 + row) * K + kt + c * 8]);
      }
    }
    __syncthreads();
    bf16x8 af[4], bfr[4];
    #pragma unroll
    for (int i = 0; i < 4; ++i) {
      af[i]  = *reinterpret_cast<const bf16x8*>(&lA[(wm + i * 16 + lr) * 32 + lg * 8]);
      bfr[i] = *reinterpret_cast<const bf16x8*>(&lB[(wn + i * 16 + lr) * 32 + lg * 8]);
    }
    #pragma unroll
    for (int mi = 0; mi < 4; ++mi)
      #pragma unroll
      for (int ni = 0; ni < 4; ++ni)
        acc[mi][ni] = __builtin_amdgcn_mfma_f32_16x16x32_bf16(af[mi], bfr[ni], acc[mi][ni], 0, 0, 0);
    __syncthreads();
  }
  #pragma unroll
  for (int mi = 0; mi < 4; ++mi)
    #pragma unroll
    for (int ni = 0; ni < 4; ++ni) {
      int col = n0 + wn + ni * 16 + lr;
      float bv = bias[col];
      #pragma unroll
      for (int r = 0; r < 4; ++r) {
        int row = m0 + wm + mi * 16 + lg * 4 + r;
        float val = (acc[mi][ni][r] + bv) * scale;
        if (OUT_MODE == 2) {
          ((float*)Outv)[(size_t)row * N + col] = val;
        } else {
          int b = row >> 11, s = row & 2047, h = col >> 6, hd = col & 63;
          u16* O = (u16*)Outv;
          if (OUT_MODE == 0) O[((size_t)(b * 16 + h) * 2048 + s) * 64 + hd] = f2bf(val);
          else               O[((size_t)(b * 16 + h) * 64 + hd) * 2048 + s] = f2bf(val);
        }
      }
    }
}

// ---------------- causal flash attention, 128 q-rows/block, swizzled LDS -------
// grid (16, 32) desc-qt; 4 waves x 32 q-rows. Q prescaled by QSCALE (log2 domain).
__global__ __launch_bounds__(256) void attn_kernel2(
    const u16* __restrict__ Qh, const u16* __restrict__ Kh,
    const u16* __restrict__ Vt, u16* __restrict__ Oa)
{
  __shared__ __align__(16) u16 lK[64 * 64];
  __shared__ __align__(16) u16 lV[64 * 64];   // [d][k]
  __shared__ __align__(16) u16 lP[4][32 * 64];
  const int qt = 15 - blockIdx.x, bh = blockIdx.y;
  const int b = bh >> 4, h = bh & 15;
  const int q0 = qt * 128;
  const u16* Qb = Qh + (size_t)bh * 2048 * 64;
  const u16* Kb = Kh + (size_t)bh * 2048 * 64;
  const u16* Vb = Vt + (size_t)bh * 64 * 2048;
  const int tid = threadIdx.x, w = tid >> 6, lane = tid & 63, lr = lane & 15, lg = lane >> 4;
  const int lrow8 = lane >> 3, lc = lane & 7;
  const int schunk = (lc ^ lrow8) * 8;
  const int wbase = q0 + w * 32;

  bf16x8 aq[2][2];
  #pragma unroll
  for (int mi = 0; mi < 2; ++mi) {
    int qrow = wbase + mi * 16 + lr;
    aq[mi][0] = *reinterpret_cast<const bf16x8*>(&Qb[(size_t)qrow * 64 + lg * 8]);
    aq[mi][1] = *reinterpret_cast<const bf16x8*>(&Qb[(size_t)qrow * 64 + 32 + lg * 8]);
  }
  f32x4 oacc[2][4] = {};
  float mrow[2][4], lsum[2][4];
  #pragma unroll
  for (int mi = 0; mi < 2; ++mi)
    #pragma unroll
    for (int r = 0; r < 4; ++r) { mrow[mi][r] = -3e38f; lsum[mi][r] = 0.f; }

  const int nkt = 2 * qt + 2;
  for (int kt = 0; kt < nkt; ++kt) {
    #pragma unroll
    for (int c = 0; c < 2; ++c) {
      int row = w * 16 + c * 8 + lrow8;
      gl_lds16(Kb + (size_t)(kt * 64 + row) * 64 + schunk, &lK[(w * 16 + c * 8) * 64]);
      gl_lds16(Vb + (size_t)row * 2048 + kt * 64 + schunk, &lV[(w * 16 + c * 8) * 64]);
    }
    __syncthreads();

    f32x4 sc[2][4] = {};
    #pragma unroll
    for (int nf = 0; nf < 4; ++nf) {
      int r = nf * 16 + lr;
      bf16x8 b0 = *reinterpret_cast<const bf16x8*>(&lK[r * 64 + ((lg ^ (r & 7)) * 8)]);
      bf16x8 b1 = *reinterpret_cast<const bf16x8*>(&lK[r * 64 + (((4 + lg) ^ (r & 7)) * 8)]);
      __builtin_amdgcn_s_setprio(1);
      #pragma unroll
      for (int mi = 0; mi < 2; ++mi) {
        sc[mi][nf] = __builtin_amdgcn_mfma_f32_16x16x32_bf16(aq[mi][0], b0, sc[mi][nf], 0, 0, 0);
        sc[mi][nf] = __builtin_amdgcn_mfma_f32_16x16x32_bf16(aq[mi][1], b1, sc[mi][nf], 0, 0, 0);
      }
      __builtin_amdgcn_s_setprio(0);
    }

    const bool maskt = (kt >= 2 * qt);
    float pm[2][4];
    #pragma unroll
    for (int mi = 0; mi < 2; ++mi)
      #pragma unroll
      for (int r = 0; r < 4; ++r) pm[mi][r] = -3e38f;
    #pragma unroll
    for (int mi = 0; mi < 2; ++mi)
      #pragma unroll
      for (int nf = 0; nf < 4; ++nf)
        #pragma unroll
        for (int r = 0; r < 4; ++r) {
          float s = sc[mi][nf][r];
          if (maskt && (kt * 64 + nf * 16 + lr) > (wbase + mi * 16 + lg * 4 + r)) s = -1e30f;
          sc[mi][nf][r] = s;
          pm[mi][r] = fmaxf(pm[mi][r], s);
        }
    float al[2][4], rs[2][4];
    #pragma unroll
    for (int mi = 0; mi < 2; ++mi)
      #pragma unroll
      for (int r = 0; r < 4; ++r) {
        #pragma unroll
        for (int x = 1; x < 16; x <<= 1) pm[mi][r] = fmaxf(pm[mi][r], __shfl_xor(pm[mi][r], x));
        float mn = fmaxf(mrow[mi][r], pm[mi][r]);
        al[mi][r] = exp2f(mrow[mi][r] - mn);
        mrow[mi][r] = mn;
        rs[mi][r] = 0.f;
      }
    #pragma unroll
    for (int mi = 0; mi < 2; ++mi)
      #pragma unroll
      for (int nf = 0; nf < 4; ++nf)
        #pragma unroll
        for (int r = 0; r < 4; ++r) {
          float p = exp2f(sc[mi][nf][r] - mrow[mi][r]);
          sc[mi][nf][r] = p;
          rs[mi][r] += p;
        }
    #pragma unroll
    for (int mi = 0; mi < 2; ++mi)
      #pragma unroll
      for (int r = 0; r < 4; ++r) {
        #pragma unroll
        for (int x = 1; x < 16; x <<= 1) rs[mi][r] += __shfl_xor(rs[mi][r], x);
        lsum[mi][r] = lsum[mi][r] * al[mi][r] + rs[mi][r];
      }
    #pragma unroll
    for (int mi = 0; mi < 2; ++mi)
      #pragma unroll
      for (int df = 0; df < 4; ++df)
        #pragma unroll
        for (int r = 0; r < 4; ++r) oacc[mi][df][r] *= al[mi][r];

    // P -> per-wave LDS (swizzled), reload as A-fragments
    u16* pw = lP[w];
    #pragma unroll
    for (int mi = 0; mi < 2; ++mi)
      #pragma unroll
      for (int nf = 0; nf < 4; ++nf)
        #pragma unroll
        for (int r = 0; r < 4; ++r) {
          int prow = mi * 16 + lg * 4 + r, col = nf * 16 + lr;
          pw[prow * 64 + (((col >> 3) ^ (prow & 7)) * 8) + (col & 7)] = f2bf(sc[mi][nf][r]);
        }
    bf16x8 pa[2][2];
    #pragma unroll
    for (int mi = 0; mi < 2; ++mi) {
      int r = mi * 16 + lr;
      pa[mi][0] = *reinterpret_cast<const bf16x8*>(&pw[r * 64 + ((lg ^ (r & 7)) * 8)]);
      pa[mi][1] = *reinterpret_cast<const bf16x8*>(&pw[r * 64 + (((4 + lg) ^ (r & 7)) * 8)]);
    }
    #pragma unroll
    for (int df = 0; df < 4; ++df) {
      int r = df * 16 + lr;
      bf16x8 v0 = *reinterpret_cast<const bf16x8*>(&lV[r * 64 + ((lg ^ (r & 7)) * 8)]);
      bf16x8 v1 = *reinterpret_cast<const bf16x8*>(&lV[r * 64 + (((4 + lg) ^ (r & 7)) * 8)]);
      __builtin_amdgcn_s_setprio(1);
      #pragma unroll
      for (int mi = 0; mi < 2; ++mi) {
        oacc[mi][df] = __builtin_amdgcn_mfma_f32_16x16x32_bf16(pa[mi][0], v0, oacc[mi][df], 0, 0, 0);
        oacc[mi][df] = __builtin_amdgcn_mfma_f32_16x16x32_bf16(pa[mi][1], v1, oacc[mi][df], 0, 0, 0);
      }
      __builtin_amdgcn_s_setprio(0);
    }
    __syncthreads();
  }

  #pragma unroll
  for (int mi = 0; mi < 2; ++mi)
    #pragma unroll
    for (int df = 0; df < 4; ++df)
      #pragma unroll
      for (int r = 0; r < 4; ++r) {
        int s = wbase + mi * 16 + lg * 4 + r;
        int d = df * 16 + lr;
        Oa[(size_t)(b * 2048 + s) * 1024 + h * 64 + d] = f2bf(oacc[mi][df][r] / lsum[mi][r]);
      }
}

extern "C" void kernel_launch(void* const* d_in, const int* in_sizes, int n_in,
                              void* d_out, int out_size, void* d_ws, size_t ws_size,
                              hipStream_t stream) {
  const float* q  = (const float*)d_in[0];
  const float* k  = (const float*)d_in[1];
  const float* v  = (const float*)d_in[2];
  const float* Wq = (const float*)d_in[4];
  const float* bq = (const float*)d_in[5];
  const float* Wk = (const float*)d_in[6];
  const float* bk = (const float*)d_in[7];
  const float* Wv = (const float*)d_in[8];
  const float* bv = (const float*)d_in[9];
  const float* Wf = (const float*)d_in[10];
  const float* bf = (const float*)d_in[11];

  if (ws_size >= ((size_t)64 << 20)) {
    u16* wsb = (u16*)d_ws;
    u16* qb  = wsb;
    u16* wqb = wsb + ((size_t)3 << 22);
    u16* wkb = wqb + (1u << 20);
    u16* wvb = wkb + (1u << 20);
    u16* wfb = wvb + (1u << 20);
    u16* Qh  = wsb + ((size_t)1 << 24);
    u16* Kh  = Qh + (1u << 22);
    u16* Vt  = Kh + (1u << 22);
    u16* Oa  = Vt + (1u << 22);
    u16* kb  = wsb + (1u << 22);
    u16* vb  = wsb + ((size_t)2 << 22);

    conv_kernel<<<8192, 256, 0, stream>>>(q, k, v, Wq, Wk, Wv, Wf, wsb);

    GArg gq{qb, wqb, bq, Qh, 0, QSCALE};
    GArg gk{kb, wkb, bk, Kh, 0, 1.0f};
    GArg gv{vb, wvb, bv, Vt, 1, 1.0f};
    gemm_bf<128><<<dim3(8, 32, 3), 256, 0, stream>>>(gq, gk, gv);

    attn_kernel2<<<dim3(16, 32), 256, 0, stream>>>(Qh, Kh, Vt, Oa);

    GArg gf{Oa, wfb, bf, d_out, 2, 1.0f};
    gemm_bf<64><<<dim3(8, 64, 1), 256, 0, stream>>>(gf, gf, gf);
  } else {
    // fallback: fp32-staging GEMMs (32 MB ws)
    u16* Qh = (u16*)d_ws;
    u16* Kh = Qh + (size_t)4096 * 1024;
    u16* Vt = Kh + (size_t)4096 * 1024;
    u16* Oa = Vt + (size_t)4096 * 1024;
    dim3 gg(8, 32), gb(256);
    gemm_legacy<0, 0><<<gg, gb, 0, stream>>>(q, Wq, bq, Qh, QSCALE);
    gemm_legacy<0, 0><<<gg, gb, 0, stream>>>(k, Wk, bk, Kh, 1.0f);
    gemm_legacy<0, 1><<<gg, gb, 0, stream>>>(v, Wv, bv, Vt, 1.0f);
    attn_kernel2<<<dim3(16, 32), gb, 0, stream>>>(Qh, Kh, Vt, Oa);
    gemm_legacy<1, 2><<<gg, gb, 0, stream>>>(Oa, Wf, bf, (float*)d_out, 1.0f);
  }
}

// Round 3
// 153.546 us; speedup vs baseline: 2.0646x; 1.3751x over previous
//
#include <hip/hip_runtime.h>

typedef __attribute__((ext_vector_type(4))) float f32x4;
typedef __attribute__((ext_vector_type(8))) short bf16x8;
typedef unsigned short u16;
typedef unsigned int u32;

#define QSCALE 0.18033688011112042f  // (1/sqrt(64)) * log2(e), folded into Q proj

__device__ __forceinline__ u16 f2bf(float f) {
  union { float f; u32 u; } v; v.f = f;
  u32 r = v.u + 0x7fffu + ((v.u >> 16) & 1u);
  return (u16)(r >> 16);
}

// async global->LDS, 16B per lane; LDS dest = base + lane*16 (wave-uniform base)
__device__ __forceinline__ void gl_lds16(const u16* g, u16* l) {
  __builtin_amdgcn_global_load_lds((const __attribute__((address_space(1))) u32*)g,
                                   (__attribute__((address_space(3))) u32*)l, 16, 0, 0);
}

// ---------------- fp32 -> bf16 bulk convert (q,k,v,Wq,Wk,Wv,Wf) ----------------
__global__ __launch_bounds__(256) void conv_kernel(
    const float* __restrict__ q, const float* __restrict__ k, const float* __restrict__ v,
    const float* __restrict__ wq, const float* __restrict__ wk, const float* __restrict__ wv,
    const float* __restrict__ wf, u16* __restrict__ dst)
{
  size_t i = ((size_t)blockIdx.x * 256 + threadIdx.x) * 8;  // 16M elems total
  const float* src; size_t off;
  if (i < ((size_t)3 << 22)) {
    int a = (int)(i >> 22);
    src = (a == 0) ? q : ((a == 1) ? k : v);
    off = i & ((1u << 22) - 1);
  } else {
    size_t j = i - ((size_t)3 << 22);
    int a = (int)(j >> 20);
    src = (a == 0) ? wq : ((a == 1) ? wk : ((a == 2) ? wv : wf));
    off = j & ((1u << 20) - 1);
  }
  float4 x0 = *reinterpret_cast<const float4*>(src + off);
  float4 x1 = *reinterpret_cast<const float4*>(src + off + 4);
  u16 o[8] = {f2bf(x0.x), f2bf(x0.y), f2bf(x0.z), f2bf(x0.w),
              f2bf(x1.x), f2bf(x1.y), f2bf(x1.z), f2bf(x1.w)};
  *reinterpret_cast<uint4*>(dst + i) = *reinterpret_cast<const uint4*>(o);
}

// ---------------- bf16 GEMM: C[M,N]=X[M,K]@W[N,K]^T+b ; BK=64, swizzled LDS ----
struct GArg {
  const u16* X; const u16* W; const float* bias; void* out; int mode; float scale;
};

template<int BM>
__global__ __launch_bounds__(256) void gemm_bf(GArg a0, GArg a1, GArg a2) {
  constexpr int K = 1024, N = 1024;
  constexpr int WNw = (BM == 128) ? 2 : 4;
  constexpr int NI  = (128 / WNw) / 16;
  constexpr int CA  = BM / 32;
  __shared__ __align__(16) u16 lA[BM * 64];
  __shared__ __align__(16) u16 lB[128 * 64];
  GArg a = (blockIdx.z == 0) ? a0 : ((blockIdx.z == 1) ? a1 : a2);
  const int n0 = blockIdx.x * 128, m0 = blockIdx.y * BM;
  const int tid = threadIdx.x, w = tid >> 6, lane = tid & 63;
  const int lr = lane & 15, lg = lane >> 4;
  const int wm = (w / WNw) * 64, wn = (w % WNw) * (128 / WNw);
  const int lrow8 = lane >> 3, lc = lane & 7;
  const int schunk = (lc ^ lrow8) * 8;

  f32x4 acc[4][NI] = {};

  for (int kt = 0; kt < K; kt += 64) {
    #pragma unroll
    for (int c = 0; c < CA; ++c) {
      int row = w * (BM / 4) + c * 8 + lrow8;
      gl_lds16(a.X + (size_t)(m0 + row) * K + kt + schunk, &lA[(w * (BM / 4) + c * 8) * 64]);
    }
    #pragma unroll
    for (int c = 0; c < 4; ++c) {
      int row = w * 32 + c * 8 + lrow8;
      gl_lds16(a.W + (size_t)(n0 + row) * K + kt + schunk, &lB[(w * 32 + c * 8) * 64]);
    }
    __syncthreads();
    #pragma unroll
    for (int h = 0; h < 2; ++h) {
      bf16x8 af[4], bfv[NI];
      #pragma unroll
      for (int i = 0; i < 4; ++i) {
        int r = wm + i * 16 + lr;
        af[i] = *reinterpret_cast<const bf16x8*>(&lA[r * 64 + (((h * 4 + lg) ^ (r & 7)) * 8)]);
      }
      #pragma unroll
      for (int i = 0; i < NI; ++i) {
        int r = wn + i * 16 + lr;
        bfv[i] = *reinterpret_cast<const bf16x8*>(&lB[r * 64 + (((h * 4 + lg) ^ (r & 7)) * 8)]);
      }
      __builtin_amdgcn_s_setprio(1);
      #pragma unroll
      for (int mi = 0; mi < 4; ++mi)
        #pragma unroll
        for (int ni = 0; ni < NI; ++ni)
          acc[mi][ni] = __builtin_amdgcn_mfma_f32_16x16x32_bf16(af[mi], bfv[ni], acc[mi][ni], 0, 0, 0);
      __builtin_amdgcn_s_setprio(0);
    }
    __syncthreads();
  }

  #pragma unroll
  for (int mi = 0; mi < 4; ++mi) {
    #pragma unroll
    for (int ni = 0; ni < NI; ++ni) {
      int col = n0 + wn + ni * 16 + lr;
      float bv = a.bias[col];
      #pragma unroll
      for (int r = 0; r < 4; ++r) {
        int row = m0 + wm + mi * 16 + lg * 4 + r;
        float val = (acc[mi][ni][r] + bv) * a.scale;
        if (a.mode == 2) {
          ((float*)a.out)[(size_t)row * N + col] = val;
        } else {
          int b = row >> 11, s = row & 2047, hh = col >> 6, hd = col & 63;
          u16* O = (u16*)a.out;
          if (a.mode == 0) O[((size_t)(b * 16 + hh) * 2048 + s) * 64 + hd] = f2bf(val);
          else             O[((size_t)(b * 16 + hh) * 64 + hd) * 2048 + s] = f2bf(val);
        }
      }
    }
  }
}

// ---------------- legacy fp32-staging GEMM (ws fallback) -----------------------
template<int IN_BF16, int OUT_MODE>
__global__ __launch_bounds__(256) void gemm_legacy(
    const void* __restrict__ Xv, const float* __restrict__ W,
    const float* __restrict__ bias, void* __restrict__ Outv, float scale)
{
  constexpr int N = 1024, K = 1024;
  __shared__ __align__(16) u16 lA[128 * 32];
  __shared__ __align__(16) u16 lB[128 * 32];
  const int n0 = blockIdx.x * 128, m0 = blockIdx.y * 128;
  const int tid = threadIdx.x;
  const int w = tid >> 6, lane = tid & 63, lr = lane & 15, lg = lane >> 4;
  const int wm = (w >> 1) * 64, wn = (w & 1) * 64;
  f32x4 acc[4][4] = {};
  for (int kt = 0; kt < K; kt += 32) {
    #pragma unroll
    for (int it = 0; it < 4; ++it) {
      int idx = it * 256 + tid, row = idx >> 3, c4 = idx & 7;
      float4 xv = *reinterpret_cast<const float4*>(&W[(size_t)(n0 + row) * K + kt + c4 * 4]);
      u16* dst = &lB[row * 32 + c4 * 4];
      dst[0] = f2bf(xv.x); dst[1] = f2bf(xv.y); dst[2] = f2bf(xv.z); dst[3] = f2bf(xv.w);
    }
    if (IN_BF16 == 0) {
      const float* X = (const float*)Xv;
      #pragma unroll
      for (int it = 0; it < 4; ++it) {
        int idx = it * 256 + tid, row = idx >> 3, c4 = idx & 7;
        float4 xv = *reinterpret_cast<const float4*>(&X[(size_t)(m0 + row) * K + kt + c4 * 4]);
        u16* dst = &lA[row * 32 + c4 * 4];
        dst[0] = f2bf(xv.x); dst[1] = f2bf(xv.y); dst[2] = f2bf(xv.z); dst[3] = f2bf(xv.w);
      }
    } else {
      const u16* X = (const u16*)Xv;
      #pragma unroll
      for (int it = 0; it < 2; ++it) {
        int idx = it * 256 + tid, row = idx >> 2, c = idx & 3;
        *reinterpret_cast<uint4*>(&lA[row * 32 + c * 8]) =
            *reinterpret_cast<const uint4*>(&X[(size_t)(m0 + row) * K + kt + c * 8]);
      }
    }
    __syncthreads();
    bf16x8 af[4], bfr[4];
    #pragma unroll
    for (int i = 0; i < 4; ++i) {
      af[i]  = *reinterpret_cast<const bf16x8*>(&lA[(wm + i * 16 + lr) * 32 + lg * 8]);
      bfr[i] = *reinterpret_cast<const bf16x8*>(&lB[(wn + i * 16 + lr) * 32 + lg * 8]);
    }
    #pragma unroll
    for (int mi = 0; mi < 4; ++mi)
      #pragma unroll
      for (int ni = 0; ni < 4; ++ni)
        acc[mi][ni] = __builtin_amdgcn_mfma_f32_16x16x32_bf16(af[mi], bfr[ni], acc[mi][ni], 0, 0, 0);
    __syncthreads();
  }
  #pragma unroll
  for (int mi = 0; mi < 4; ++mi)
    #pragma unroll
    for (int ni = 0; ni < 4; ++ni) {
      int col = n0 + wn + ni * 16 + lr;
      float bv = bias[col];
      #pragma unroll
      for (int r = 0; r < 4; ++r) {
        int row = m0 + wm + mi * 16 + lg * 4 + r;
        float val = (acc[mi][ni][r] + bv) * scale;
        if (OUT_MODE == 2) {
          ((float*)Outv)[(size_t)row * N + col] = val;
        } else {
          int b = row >> 11, s = row & 2047, h = col >> 6, hd = col & 63;
          u16* O = (u16*)Outv;
          if (OUT_MODE == 0) O[((size_t)(b * 16 + h) * 2048 + s) * 64 + hd] = f2bf(val);
          else               O[((size_t)(b * 16 + h) * 64 + hd) * 2048 + s] = f2bf(val);
        }
      }
    }
}

// ---------------- causal flash attention, balanced dual-tile blocks ------------
// grid (16, 32). Block x handles 64-row q-tiles tA=x and tB=31-x (uniform work:
// 33 tile-units). 4 waves x 16 q-rows per tile. Q prescaled by QSCALE (log2 dom).
// lsum via MFMA-ones; defer-max rescale (THR=8 in log2 units).

__device__ __forceinline__ void seg_step(
    const bf16x8* aq, f32x4* oacc, float* mr, float* ls,
    const u16* lK, const u16* lV, u16* pw,
    bool diag, int col0, int rowg0, int lr, int lg, bf16x8 ones)
{
  f32x4 sc[4] = {};
  #pragma unroll
  for (int nf = 0; nf < 4; ++nf) {
    int r = nf * 16 + lr;
    bf16x8 b0 = *reinterpret_cast<const bf16x8*>(&lK[r * 64 + ((lg ^ (r & 7)) * 8)]);
    bf16x8 b1 = *reinterpret_cast<const bf16x8*>(&lK[r * 64 + (((4 + lg) ^ (r & 7)) * 8)]);
    __builtin_amdgcn_s_setprio(1);
    sc[nf] = __builtin_amdgcn_mfma_f32_16x16x32_bf16(aq[0], b0, sc[nf], 0, 0, 0);
    sc[nf] = __builtin_amdgcn_mfma_f32_16x16x32_bf16(aq[1], b1, sc[nf], 0, 0, 0);
    __builtin_amdgcn_s_setprio(0);
  }
  float pm[4] = {-3e38f, -3e38f, -3e38f, -3e38f};
  #pragma unroll
  for (int nf = 0; nf < 4; ++nf)
    #pragma unroll
    for (int r = 0; r < 4; ++r) {
      float s = sc[nf][r];
      if (diag && (col0 + nf * 16 + lr) > (rowg0 + lg * 4 + r)) s = -1e30f;
      sc[nf][r] = s;
      pm[r] = fmaxf(pm[r], s);
    }
  #pragma unroll
  for (int r = 0; r < 4; ++r)
    #pragma unroll
    for (int x = 1; x < 16; x <<= 1) pm[r] = fmaxf(pm[r], __shfl_xor(pm[r], x));
  float need = 0.f;
  #pragma unroll
  for (int r = 0; r < 4; ++r) need = fmaxf(need, pm[r] - mr[r]);
  if (__any(need > 8.0f)) {
    #pragma unroll
    for (int r = 0; r < 4; ++r) {
      float mn = fmaxf(mr[r], pm[r]);
      float al = exp2f(mr[r] - mn);
      mr[r] = mn;
      ls[r] *= al;
      #pragma unroll
      for (int df = 0; df < 4; ++df) oacc[df][r] *= al;
    }
  }
  #pragma unroll
  for (int nf = 0; nf < 4; ++nf)
    #pragma unroll
    for (int r = 0; r < 4; ++r) {
      float p = exp2f(sc[nf][r] - mr[r]);
      int prow = lg * 4 + r, col = nf * 16 + lr;
      pw[prow * 64 + (((col >> 3) ^ (prow & 7)) * 8) + (col & 7)] = f2bf(p);
    }
  bf16x8 pa0 = *reinterpret_cast<const bf16x8*>(&pw[lr * 64 + ((lg ^ (lr & 7)) * 8)]);
  bf16x8 pa1 = *reinterpret_cast<const bf16x8*>(&pw[lr * 64 + (((4 + lg) ^ (lr & 7)) * 8)]);
  f32x4 rs = {};
  rs = __builtin_amdgcn_mfma_f32_16x16x32_bf16(pa1, ones, rs, 0, 0, 0);
  rs = __builtin_amdgcn_mfma_f32_16x16x32_bf16(pa0, ones, rs, 0, 0, 0);
  #pragma unroll
  for (int r = 0; r < 4; ++r) ls[r] += rs[r];
  #pragma unroll
  for (int df = 0; df < 4; ++df) {
    int r = df * 16 + lr;
    bf16x8 v0 = *reinterpret_cast<const bf16x8*>(&lV[r * 64 + ((lg ^ (r & 7)) * 8)]);
    bf16x8 v1 = *reinterpret_cast<const bf16x8*>(&lV[r * 64 + (((4 + lg) ^ (r & 7)) * 8)]);
    __builtin_amdgcn_s_setprio(1);
    oacc[df] = __builtin_amdgcn_mfma_f32_16x16x32_bf16(pa0, v0, oacc[df], 0, 0, 0);
    oacc[df] = __builtin_amdgcn_mfma_f32_16x16x32_bf16(pa1, v1, oacc[df], 0, 0, 0);
    __builtin_amdgcn_s_setprio(0);
  }
}

__global__ __launch_bounds__(256) void attn_kernel3(
    const u16* __restrict__ Qh, const u16* __restrict__ Kh,
    const u16* __restrict__ Vt, u16* __restrict__ Oa)
{
  __shared__ __align__(16) u16 lK[64 * 64];
  __shared__ __align__(16) u16 lV[64 * 64];
  __shared__ __align__(16) u16 lP[4][16 * 64];
  const int x = blockIdx.x, bh = blockIdx.y;
  const int b = bh >> 4, h = bh & 15;
  const int tA = x, tB = 31 - x;
  const u16* Qb = Qh + (size_t)bh * 2048 * 64;
  const u16* Kb = Kh + (size_t)bh * 2048 * 64;
  const u16* Vb = Vt + (size_t)bh * 64 * 2048;
  const int tid = threadIdx.x, w = tid >> 6, lane = tid & 63;
  const int lr = lane & 15, lg = lane >> 4;
  const int lrow8 = lane >> 3, lc = lane & 7;
  const int schunk = (lc ^ lrow8) * 8;

  bf16x8 ones;
  #pragma unroll
  for (int j = 0; j < 8; ++j) ones[j] = (short)0x3F80;

  bf16x8 aqA[2], aqB[2];
  {
    int qrA = tA * 64 + w * 16 + lr;
    int qrB = tB * 64 + w * 16 + lr;
    aqA[0] = *reinterpret_cast<const bf16x8*>(&Qb[(size_t)qrA * 64 + lg * 8]);
    aqA[1] = *reinterpret_cast<const bf16x8*>(&Qb[(size_t)qrA * 64 + 32 + lg * 8]);
    aqB[0] = *reinterpret_cast<const bf16x8*>(&Qb[(size_t)qrB * 64 + lg * 8]);
    aqB[1] = *reinterpret_cast<const bf16x8*>(&Qb[(size_t)qrB * 64 + 32 + lg * 8]);
  }
  f32x4 oA[4] = {}, oB[4] = {};
  float mrA[4], lsA[4], mrB[4], lsB[4];
  #pragma unroll
  for (int r = 0; r < 4; ++r) { mrA[r] = -3e38f; lsA[r] = 0.f; mrB[r] = -3e38f; lsB[r] = 0.f; }
  const int rowgA = tA * 64 + w * 16, rowgB = tB * 64 + w * 16;

  const int nkt = tB + 1;
  for (int kt = 0; kt < nkt; ++kt) {
    #pragma unroll
    for (int c = 0; c < 2; ++c) {
      int row = w * 16 + c * 8 + lrow8;
      gl_lds16(Kb + (size_t)(kt * 64 + row) * 64 + schunk, &lK[(w * 16 + c * 8) * 64]);
      gl_lds16(Vb + (size_t)row * 2048 + kt * 64 + schunk, &lV[(w * 16 + c * 8) * 64]);
    }
    __syncthreads();
    seg_step(aqB, oB, mrB, lsB, lK, lV, lP[w], kt == tB, kt * 64, rowgB, lr, lg, ones);
    if (kt <= tA)
      seg_step(aqA, oA, mrA, lsA, lK, lV, lP[w], kt == tA, kt * 64, rowgA, lr, lg, ones);
    __syncthreads();
  }

  #pragma unroll
  for (int df = 0; df < 4; ++df)
    #pragma unroll
    for (int r = 0; r < 4; ++r) {
      int d = df * 16 + lr;
      int sA = rowgA + lg * 4 + r, sB = rowgB + lg * 4 + r;
      Oa[(size_t)(b * 2048 + sA) * 1024 + h * 64 + d] = f2bf(oA[df][r] / lsA[r]);
      Oa[(size_t)(b * 2048 + sB) * 1024 + h * 64 + d] = f2bf(oB[df][r] / lsB[r]);
    }
}

extern "C" void kernel_launch(void* const* d_in, const int* in_sizes, int n_in,
                              void* d_out, int out_size, void* d_ws, size_t ws_size,
                              hipStream_t stream) {
  const float* q  = (const float*)d_in[0];
  const float* k  = (const float*)d_in[1];
  const float* v  = (const float*)d_in[2];
  const float* Wq = (const float*)d_in[4];
  const float* bq = (const float*)d_in[5];
  const float* Wk = (const float*)d_in[6];
  const float* bk = (const float*)d_in[7];
  const float* Wv = (const float*)d_in[8];
  const float* bv = (const float*)d_in[9];
  const float* Wf = (const float*)d_in[10];
  const float* bf = (const float*)d_in[11];

  if (ws_size >= ((size_t)64 << 20)) {
    u16* wsb = (u16*)d_ws;
    u16* qb  = wsb;
    u16* wqb = wsb + ((size_t)3 << 22);
    u16* wkb = wqb + (1u << 20);
    u16* wvb = wkb + (1u << 20);
    u16* wfb = wvb + (1u << 20);
    u16* Qh  = wsb + ((size_t)1 << 24);
    u16* Kh  = Qh + (1u << 22);
    u16* Vt  = Kh + (1u << 22);
    u16* Oa  = Vt + (1u << 22);
    u16* kb  = wsb + (1u << 22);
    u16* vb  = wsb + ((size_t)2 << 22);

    conv_kernel<<<8192, 256, 0, stream>>>(q, k, v, Wq, Wk, Wv, Wf, wsb);

    GArg gq{qb, wqb, bq, Qh, 0, QSCALE};
    GArg gk{kb, wkb, bk, Kh, 0, 1.0f};
    GArg gv{vb, wvb, bv, Vt, 1, 1.0f};
    gemm_bf<128><<<dim3(8, 32, 3), 256, 0, stream>>>(gq, gk, gv);

    attn_kernel3<<<dim3(16, 32), 256, 0, stream>>>(Qh, Kh, Vt, Oa);

    GArg gf{Oa, wfb, bf, d_out, 2, 1.0f};
    gemm_bf<64><<<dim3(8, 64, 1), 256, 0, stream>>>(gf, gf, gf);
  } else {
    // fallback: fp32-staging GEMMs (32 MB ws)
    u16* Qh = (u16*)d_ws;
    u16* Kh = Qh + (size_t)4096 * 1024;
    u16* Vt = Kh + (size_t)4096 * 1024;
    u16* Oa = Vt + (size_t)4096 * 1024;
    dim3 gg(8, 32), gb(256);
    gemm_legacy<0, 0><<<gg, gb, 0, stream>>>(q, Wq, bq, Qh, QSCALE);
    gemm_legacy<0, 0><<<gg, gb, 0, stream>>>(k, Wk, bk, Kh, 1.0f);
    gemm_legacy<0, 1><<<gg, gb, 0, stream>>>(v, Wv, bv, Vt, 1.0f);
    attn_kernel3<<<dim3(16, 32), gb, 0, stream>>>(Qh, Kh, Vt, Oa);
    gemm_legacy<1, 2><<<gg, gb, 0, stream>>>(Oa, Wf, bf, (float*)d_out, 1.0f);
  }
}

// Round 4
// 141.737 us; speedup vs baseline: 2.2366x; 1.0833x over previous
//
#include <hip/hip_runtime.h>

typedef __attribute__((ext_vector_type(4))) float f32x4;
typedef __attribute__((ext_vector_type(8))) short bf16x8;
typedef unsigned short u16;
typedef unsigned int u32;

#define QSCALE 0.18033688011112042f  // (1/sqrt(64)) * log2(e), folded into Q proj

__device__ __forceinline__ u16 f2bf(float f) {
  union { float f; u32 u; } v; v.f = f;
  u32 r = v.u + 0x7fffu + ((v.u >> 16) & 1u);
  return (u16)(r >> 16);
}

// async global->LDS, 16B per lane; LDS dest = base + lane*16 (wave-uniform base)
__device__ __forceinline__ void gl_lds16(const u16* g, u16* l) {
  __builtin_amdgcn_global_load_lds((const __attribute__((address_space(1))) u32*)g,
                                   (__attribute__((address_space(3))) u32*)l, 16, 0, 0);
}

// ---------------- fp32 -> bf16 bulk convert (q,k,v,Wq,Wk,Wv,Wf) ----------------
__global__ __launch_bounds__(256) void conv_kernel(
    const float* __restrict__ q, const float* __restrict__ k, const float* __restrict__ v,
    const float* __restrict__ wq, const float* __restrict__ wk, const float* __restrict__ wv,
    const float* __restrict__ wf, u16* __restrict__ dst)
{
  size_t i = ((size_t)blockIdx.x * 256 + threadIdx.x) * 8;  // 16M elems total
  const float* src; size_t off;
  if (i < ((size_t)3 << 22)) {
    int a = (int)(i >> 22);
    src = (a == 0) ? q : ((a == 1) ? k : v);
    off = i & ((1u << 22) - 1);
  } else {
    size_t j = i - ((size_t)3 << 22);
    int a = (int)(j >> 20);
    src = (a == 0) ? wq : ((a == 1) ? wk : ((a == 2) ? wv : wf));
    off = j & ((1u << 20) - 1);
  }
  float4 x0 = *reinterpret_cast<const float4*>(src + off);
  float4 x1 = *reinterpret_cast<const float4*>(src + off + 4);
  u16 o[8] = {f2bf(x0.x), f2bf(x0.y), f2bf(x0.z), f2bf(x0.w),
              f2bf(x1.x), f2bf(x1.y), f2bf(x1.z), f2bf(x1.w)};
  *reinterpret_cast<uint4*>(dst + i) = *reinterpret_cast<const uint4*>(o);
}

// ---------------- bf16 GEMM: C[M,N]=X[M,K]@W[N,K]^T+b ; BK=64, swizzled LDS ----
struct GArg {
  const u16* X; const u16* W; const float* bias; void* out; int mode; float scale;
};

template<int BM>
__global__ __launch_bounds__(256) void gemm_bf(GArg a0, GArg a1, GArg a2) {
  constexpr int K = 1024, N = 1024;
  constexpr int WNw = (BM == 128) ? 2 : 4;
  constexpr int NI  = (128 / WNw) / 16;
  constexpr int CA  = BM / 32;
  __shared__ __align__(16) u16 lA[BM * 64];
  __shared__ __align__(16) u16 lB[128 * 64];
  GArg a = (blockIdx.z == 0) ? a0 : ((blockIdx.z == 1) ? a1 : a2);
  const int n0 = blockIdx.x * 128, m0 = blockIdx.y * BM;
  const int tid = threadIdx.x, w = tid >> 6, lane = tid & 63;
  const int lr = lane & 15, lg = lane >> 4;
  const int wm = (w / WNw) * 64, wn = (w % WNw) * (128 / WNw);
  const int lrow8 = lane >> 3, lc = lane & 7;
  const int schunk = (lc ^ lrow8) * 8;

  f32x4 acc[4][NI] = {};

  for (int kt = 0; kt < K; kt += 64) {
    #pragma unroll
    for (int c = 0; c < CA; ++c) {
      int row = w * (BM / 4) + c * 8 + lrow8;
      gl_lds16(a.X + (size_t)(m0 + row) * K + kt + schunk, &lA[(w * (BM / 4) + c * 8) * 64]);
    }
    #pragma unroll
    for (int c = 0; c < 4; ++c) {
      int row = w * 32 + c * 8 + lrow8;
      gl_lds16(a.W + (size_t)(n0 + row) * K + kt + schunk, &lB[(w * 32 + c * 8) * 64]);
    }
    __syncthreads();
    #pragma unroll
    for (int h = 0; h < 2; ++h) {
      bf16x8 af[4], bfv[NI];
      #pragma unroll
      for (int i = 0; i < 4; ++i) {
        int r = wm + i * 16 + lr;
        af[i] = *reinterpret_cast<const bf16x8*>(&lA[r * 64 + (((h * 4 + lg) ^ (r & 7)) * 8)]);
      }
      #pragma unroll
      for (int i = 0; i < NI; ++i) {
        int r = wn + i * 16 + lr;
        bfv[i] = *reinterpret_cast<const bf16x8*>(&lB[r * 64 + (((h * 4 + lg) ^ (r & 7)) * 8)]);
      }
      __builtin_amdgcn_s_setprio(1);
      #pragma unroll
      for (int mi = 0; mi < 4; ++mi)
        #pragma unroll
        for (int ni = 0; ni < NI; ++ni)
          acc[mi][ni] = __builtin_amdgcn_mfma_f32_16x16x32_bf16(af[mi], bfv[ni], acc[mi][ni], 0, 0, 0);
      __builtin_amdgcn_s_setprio(0);
    }
    __syncthreads();
  }

  #pragma unroll
  for (int mi = 0; mi < 4; ++mi) {
    #pragma unroll
    for (int ni = 0; ni < NI; ++ni) {
      int col = n0 + wn + ni * 16 + lr;
      float bv = a.bias[col];
      #pragma unroll
      for (int r = 0; r < 4; ++r) {
        int row = m0 + wm + mi * 16 + lg * 4 + r;
        float val = (acc[mi][ni][r] + bv) * a.scale;
        if (a.mode == 2) {
          ((float*)a.out)[(size_t)row * N + col] = val;
        } else {
          int b = row >> 11, s = row & 2047, hh = col >> 6, hd = col & 63;
          u16* O = (u16*)a.out;
          if (a.mode == 0) O[((size_t)(b * 16 + hh) * 2048 + s) * 64 + hd] = f2bf(val);
          else             O[((size_t)(b * 16 + hh) * 64 + hd) * 2048 + s] = f2bf(val);
        }
      }
    }
  }
}

// ---------------- legacy fp32-staging GEMM (ws fallback) -----------------------
template<int IN_BF16, int OUT_MODE>
__global__ __launch_bounds__(256) void gemm_legacy(
    const void* __restrict__ Xv, const float* __restrict__ W,
    const float* __restrict__ bias, void* __restrict__ Outv, float scale)
{
  constexpr int N = 1024, K = 1024;
  __shared__ __align__(16) u16 lA[128 * 32];
  __shared__ __align__(16) u16 lB[128 * 32];
  const int n0 = blockIdx.x * 128, m0 = blockIdx.y * 128;
  const int tid = threadIdx.x;
  const int w = tid >> 6, lane = tid & 63, lr = lane & 15, lg = lane >> 4;
  const int wm = (w >> 1) * 64, wn = (w & 1) * 64;
  f32x4 acc[4][4] = {};
  for (int kt = 0; kt < K; kt += 32) {
    #pragma unroll
    for (int it = 0; it < 4; ++it) {
      int idx = it * 256 + tid, row = idx >> 3, c4 = idx & 7;
      float4 xv = *reinterpret_cast<const float4*>(&W[(size_t)(n0 + row) * K + kt + c4 * 4]);
      u16* dst = &lB[row * 32 + c4 * 4];
      dst[0] = f2bf(xv.x); dst[1] = f2bf(xv.y); dst[2] = f2bf(xv.z); dst[3] = f2bf(xv.w);
    }
    if (IN_BF16 == 0) {
      const float* X = (const float*)Xv;
      #pragma unroll
      for (int it = 0; it < 4; ++it) {
        int idx = it * 256 + tid, row = idx >> 3, c4 = idx & 7;
        float4 xv = *reinterpret_cast<const float4*>(&X[(size_t)(m0 + row) * K + kt + c4 * 4]);
        u16* dst = &lA[row * 32 + c4 * 4];
        dst[0] = f2bf(xv.x); dst[1] = f2bf(xv.y); dst[2] = f2bf(xv.z); dst[3] = f2bf(xv.w);
      }
    } else {
      const u16* X = (const u16*)Xv;
      #pragma unroll
      for (int it = 0; it < 2; ++it) {
        int idx = it * 256 + tid, row = idx >> 2, c = idx & 3;
        *reinterpret_cast<uint4*>(&lA[row * 32 + c * 8]) =
            *reinterpret_cast<const uint4*>(&X[(size_t)(m0 + row) * K + kt + c * 8]);
      }
    }
    __syncthreads();
    bf16x8 af[4], bfr[4];
    #pragma unroll
    for (int i = 0; i < 4; ++i) {
      af[i]  = *reinterpret_cast<const bf16x8*>(&lA[(wm + i * 16 + lr) * 32 + lg * 8]);
      bfr[i] = *reinterpret_cast<const bf16x8*>(&lB[(wn + i * 16 + lr) * 32 + lg * 8]);
    }
    #pragma unroll
    for (int mi = 0; mi < 4; ++mi)
      #pragma unroll
      for (int ni = 0; ni < 4; ++ni)
        acc[mi][ni] = __builtin_amdgcn_mfma_f32_16x16x32_bf16(af[mi], bfr[ni], acc[mi][ni], 0, 0, 0);
    __syncthreads();
  }
  #pragma unroll
  for (int mi = 0; mi < 4; ++mi)
    #pragma unroll
    for (int ni = 0; ni < 4; ++ni) {
      int col = n0 + wn + ni * 16 + lr;
      float bv = bias[col];
      #pragma unroll
      for (int r = 0; r < 4; ++r) {
        int row = m0 + wm + mi * 16 + lg * 4 + r;
        float val = (acc[mi][ni][r] + bv) * scale;
        if (OUT_MODE == 2) {
          ((float*)Outv)[(size_t)row * N + col] = val;
        } else {
          int b = row >> 11, s = row & 2047, h = col >> 6, hd = col & 63;
          u16* O = (u16*)Outv;
          if (OUT_MODE == 0) O[((size_t)(b * 16 + h) * 2048 + s) * 64 + hd] = f2bf(val);
          else               O[((size_t)(b * 16 + h) * 64 + hd) * 2048 + s] = f2bf(val);
        }
      }
    }
}

// ---------------- causal flash attention v4 ------------------------------------
// Dual balanced 64-row q-tiles per block (tA=x, tB=31-x), 4 waves x 16 q-rows.
// Swapped QK^T (S[k][q]): per-lane q=lane&15, in-register P assembly via
// cvt_pk_bf16 + ds_bpermute (no P LDS). Double-buffered K/V staging (early issue).
// Q prescaled by QSCALE so scores are in log2 domain.

__device__ __forceinline__ void seg_step2(
    const bf16x8* aq, f32x4* oacc, float& mr, float* lh,
    const u16* lK, const u16* lV,
    bool diag, int col0, int rowg0, int lr, int lg, bf16x8 ones)
{
  // QK^T swapped: sc[nf] = K-rows(nf) x Q -> lane holds S[k=nf*16+lg*4+r][q=lr]
  f32x4 sc[4];
  #pragma unroll
  for (int nf = 0; nf < 4; ++nf) {
    int r = nf * 16 + lr;
    bf16x8 k0 = *reinterpret_cast<const bf16x8*>(&lK[r * 64 + ((lg ^ (r & 7)) * 8)]);
    bf16x8 k1 = *reinterpret_cast<const bf16x8*>(&lK[r * 64 + (((4 + lg) ^ (r & 7)) * 8)]);
    f32x4 z = {};
    __builtin_amdgcn_s_setprio(1);
    z = __builtin_amdgcn_mfma_f32_16x16x32_bf16(k0, aq[0], z, 0, 0, 0);
    z = __builtin_amdgcn_mfma_f32_16x16x32_bf16(k1, aq[1], z, 0, 0, 0);
    __builtin_amdgcn_s_setprio(0);
    sc[nf] = z;
  }
  // mask + per-lane row max (q = rowg0 + lr fixed for this lane)
  const int qv = rowg0 + lr;
  float pm = -3e38f;
  #pragma unroll
  for (int nf = 0; nf < 4; ++nf)
    #pragma unroll
    for (int r = 0; r < 4; ++r) {
      float s = sc[nf][r];
      if (diag && (col0 + nf * 16 + lg * 4 + r) > qv) s = -1e30f;
      sc[nf][r] = s;
      pm = fmaxf(pm, s);
    }
  pm = fmaxf(pm, __shfl_xor(pm, 16));
  pm = fmaxf(pm, __shfl_xor(pm, 32));
  // deferred rescale (THR = 8 in log2 units)
  if (__any(pm - mr > 8.0f)) {
    float mn = fmaxf(mr, pm);
    float al = exp2f(mr - mn);
    mr = mn;
    #pragma unroll
    for (int r = 0; r < 4; ++r) {
      float a4 = __shfl(al, lg * 4 + r);
      lh[r] *= a4;
      #pragma unroll
      for (int df = 0; df < 4; ++df) oacc[df][r] *= a4;
    }
  }
  // exp2 + pack to bf16 pairs
  u32 pk0[4], pk1[4];
  #pragma unroll
  for (int nf = 0; nf < 4; ++nf) {
    float p0 = exp2f(sc[nf][0] - mr), p1 = exp2f(sc[nf][1] - mr);
    float p2 = exp2f(sc[nf][2] - mr), p3 = exp2f(sc[nf][3] - mr);
    asm("v_cvt_pk_bf16_f32 %0, %1, %2" : "=v"(pk0[nf]) : "v"(p0), "v"(p1));
    asm("v_cvt_pk_bf16_f32 %0, %1, %2" : "=v"(pk1[nf]) : "v"(p2), "v"(p3));
  }
  // assemble PV A-fragments: dest lane (lg,lr) needs P[q=lr][k=8*lg+j]
  const int srcA = lr + 32 * (lg & 1), srcB = srcA + 16;
  const bool lo2 = (lg < 2);
  u32 w0, w1, w2, w3, w4, w5, w6, w7;
  {
    u32 a0 = __shfl((int)pk0[0], srcA), a1 = __shfl((int)pk1[0], srcA);
    u32 a2 = __shfl((int)pk0[0], srcB), a3 = __shfl((int)pk1[0], srcB);
    u32 b0 = __shfl((int)pk0[1], srcA), b1 = __shfl((int)pk1[1], srcA);
    u32 b2 = __shfl((int)pk0[1], srcB), b3 = __shfl((int)pk1[1], srcB);
    w0 = lo2 ? a0 : b0; w1 = lo2 ? a1 : b1; w2 = lo2 ? a2 : b2; w3 = lo2 ? a3 : b3;
    u32 c0 = __shfl((int)pk0[2], srcA), c1 = __shfl((int)pk1[2], srcA);
    u32 c2 = __shfl((int)pk0[2], srcB), c3 = __shfl((int)pk1[2], srcB);
    u32 d0 = __shfl((int)pk0[3], srcA), d1 = __shfl((int)pk1[3], srcA);
    u32 d2 = __shfl((int)pk0[3], srcB), d3 = __shfl((int)pk1[3], srcB);
    w4 = lo2 ? c0 : d0; w5 = lo2 ? c1 : d1; w6 = lo2 ? c2 : d2; w7 = lo2 ? c3 : d3;
  }
  union UU { u32 u[4]; bf16x8 v; };
  UU ua; ua.u[0] = w0; ua.u[1] = w1; ua.u[2] = w2; ua.u[3] = w3;
  UU ub; ub.u[0] = w4; ub.u[1] = w5; ub.u[2] = w6; ub.u[3] = w7;
  bf16x8 pa0 = ua.v, pa1 = ub.v;
  // row-sum on the matrix pipe; lands in accumulator home (row = lg*4+r)
  f32x4 rs = {};
  rs = __builtin_amdgcn_mfma_f32_16x16x32_bf16(pa0, ones, rs, 0, 0, 0);
  rs = __builtin_amdgcn_mfma_f32_16x16x32_bf16(pa1, ones, rs, 0, 0, 0);
  #pragma unroll
  for (int r = 0; r < 4; ++r) lh[r] += rs[r];
  // PV
  #pragma unroll
  for (int df = 0; df < 4; ++df) {
    int r = df * 16 + lr;
    bf16x8 v0 = *reinterpret_cast<const bf16x8*>(&lV[r * 64 + ((lg ^ (r & 7)) * 8)]);
    bf16x8 v1 = *reinterpret_cast<const bf16x8*>(&lV[r * 64 + (((4 + lg) ^ (r & 7)) * 8)]);
    __builtin_amdgcn_s_setprio(1);
    oacc[df] = __builtin_amdgcn_mfma_f32_16x16x32_bf16(pa0, v0, oacc[df], 0, 0, 0);
    oacc[df] = __builtin_amdgcn_mfma_f32_16x16x32_bf16(pa1, v1, oacc[df], 0, 0, 0);
    __builtin_amdgcn_s_setprio(0);
  }
}

__global__ __launch_bounds__(256) void attn_kernel4(
    const u16* __restrict__ Qh, const u16* __restrict__ Kh,
    const u16* __restrict__ Vt, u16* __restrict__ Oa)
{
  __shared__ __align__(16) u16 lK[2][64 * 64];
  __shared__ __align__(16) u16 lV[2][64 * 64];
  const int x = blockIdx.x, bh = blockIdx.y;
  const int b = bh >> 4, h = bh & 15;
  const int tA = x, tB = 31 - x;
  const u16* Qb = Qh + (size_t)bh * 2048 * 64;
  const u16* Kb = Kh + (size_t)bh * 2048 * 64;
  const u16* Vb = Vt + (size_t)bh * 64 * 2048;
  const int tid = threadIdx.x, w = tid >> 6, lane = tid & 63;
  const int lr = lane & 15, lg = lane >> 4;
  const int lrow8 = lane >> 3, lc = lane & 7;
  const int schunk = (lc ^ lrow8) * 8;

  bf16x8 ones;
  #pragma unroll
  for (int j = 0; j < 8; ++j) ones[j] = (short)0x3F80;

  bf16x8 aqA[2], aqB[2];
  {
    int qrA = tA * 64 + w * 16 + lr;
    int qrB = tB * 64 + w * 16 + lr;
    aqA[0] = *reinterpret_cast<const bf16x8*>(&Qb[(size_t)qrA * 64 + lg * 8]);
    aqA[1] = *reinterpret_cast<const bf16x8*>(&Qb[(size_t)qrA * 64 + 32 + lg * 8]);
    aqB[0] = *reinterpret_cast<const bf16x8*>(&Qb[(size_t)qrB * 64 + lg * 8]);
    aqB[1] = *reinterpret_cast<const bf16x8*>(&Qb[(size_t)qrB * 64 + 32 + lg * 8]);
  }
  f32x4 oA[4] = {}, oB[4] = {};
  float mrA = -3e38f, mrB = -3e38f;
  float lhA[4] = {}, lhB[4] = {};
  const int rowgA = tA * 64 + w * 16, rowgB = tB * 64 + w * 16;

  const int nkt = tB + 1;
  int cur = 0;

  // prologue: stage kt=0
  #pragma unroll
  for (int c = 0; c < 2; ++c) {
    int row = w * 16 + c * 8 + lrow8;
    gl_lds16(Kb + (size_t)(0 * 64 + row) * 64 + schunk, &lK[0][(w * 16 + c * 8) * 64]);
    gl_lds16(Vb + (size_t)row * 2048 + 0 * 64 + schunk, &lV[0][(w * 16 + c * 8) * 64]);
  }
  __syncthreads();

  for (int kt = 0; kt < nkt; ++kt) {
    if (kt + 1 < nkt) {
      #pragma unroll
      for (int c = 0; c < 2; ++c) {
        int row = w * 16 + c * 8 + lrow8;
        gl_lds16(Kb + (size_t)((kt + 1) * 64 + row) * 64 + schunk, &lK[cur ^ 1][(w * 16 + c * 8) * 64]);
        gl_lds16(Vb + (size_t)row * 2048 + (kt + 1) * 64 + schunk, &lV[cur ^ 1][(w * 16 + c * 8) * 64]);
      }
    }
    seg_step2(aqB, oB, mrB, lhB, lK[cur], lV[cur], kt == tB, kt * 64, rowgB, lr, lg, ones);
    if (kt <= tA)
      seg_step2(aqA, oA, mrA, lhA, lK[cur], lV[cur], kt == tA, kt * 64, rowgA, lr, lg, ones);
    if (kt + 1 < nkt) __syncthreads();
    cur ^= 1;
  }

  #pragma unroll
  for (int df = 0; df < 4; ++df)
    #pragma unroll
    for (int r = 0; r < 4; ++r) {
      int d = df * 16 + lr;
      int sA = rowgA + lg * 4 + r, sB = rowgB + lg * 4 + r;
      Oa[(size_t)(b * 2048 + sA) * 1024 + h * 64 + d] = f2bf(oA[df][r] / lhA[r]);
      Oa[(size_t)(b * 2048 + sB) * 1024 + h * 64 + d] = f2bf(oB[df][r] / lhB[r]);
    }
}

extern "C" void kernel_launch(void* const* d_in, const int* in_sizes, int n_in,
                              void* d_out, int out_size, void* d_ws, size_t ws_size,
                              hipStream_t stream) {
  const float* q  = (const float*)d_in[0];
  const float* k  = (const float*)d_in[1];
  const float* v  = (const float*)d_in[2];
  const float* Wq = (const float*)d_in[4];
  const float* bq = (const float*)d_in[5];
  const float* Wk = (const float*)d_in[6];
  const float* bk = (const float*)d_in[7];
  const float* Wv = (const float*)d_in[8];
  const float* bv = (const float*)d_in[9];
  const float* Wf = (const float*)d_in[10];
  const float* bf = (const float*)d_in[11];

  if (ws_size >= ((size_t)64 << 20)) {
    u16* wsb = (u16*)d_ws;
    u16* qb  = wsb;
    u16* wqb = wsb + ((size_t)3 << 22);
    u16* wkb = wqb + (1u << 20);
    u16* wvb = wkb + (1u << 20);
    u16* wfb = wvb + (1u << 20);
    u16* Qh  = wsb + ((size_t)1 << 24);
    u16* Kh  = Qh + (1u << 22);
    u16* Vt  = Kh + (1u << 22);
    u16* Oa  = Vt + (1u << 22);
    u16* kb  = wsb + (1u << 22);
    u16* vb  = wsb + ((size_t)2 << 22);

    conv_kernel<<<8192, 256, 0, stream>>>(q, k, v, Wq, Wk, Wv, Wf, wsb);

    GArg gq{qb, wqb, bq, Qh, 0, QSCALE};
    GArg gk{kb, wkb, bk, Kh, 0, 1.0f};
    GArg gv{vb, wvb, bv, Vt, 1, 1.0f};
    gemm_bf<128><<<dim3(8, 32, 3), 256, 0, stream>>>(gq, gk, gv);

    attn_kernel4<<<dim3(16, 32), 256, 0, stream>>>(Qh, Kh, Vt, Oa);

    GArg gf{Oa, wfb, bf, d_out, 2, 1.0f};
    gemm_bf<64><<<dim3(8, 64, 1), 256, 0, stream>>>(gf, gf, gf);
  } else {
    // fallback: fp32-staging GEMMs (32 MB ws)
    u16* Qh = (u16*)d_ws;
    u16* Kh = Qh + (size_t)4096 * 1024;
    u16* Vt = Kh + (size_t)4096 * 1024;
    u16* Oa = Vt + (size_t)4096 * 1024;
    dim3 gg(8, 32), gb(256);
    gemm_legacy<0, 0><<<gg, gb, 0, stream>>>(q, Wq, bq, Qh, QSCALE);
    gemm_legacy<0, 0><<<gg, gb, 0, stream>>>(k, Wk, bk, Kh, 1.0f);
    gemm_legacy<0, 1><<<gg, gb, 0, stream>>>(v, Wv, bv, Vt, 1.0f);
    attn_kernel4<<<dim3(16, 32), gb, 0, stream>>>(Qh, Kh, Vt, Oa);
    gemm_legacy<1, 2><<<gg, gb, 0, stream>>>(Oa, Wf, bf, (float*)d_out, 1.0f);
  }
}